// Round 3
// baseline (12057.069 us; speedup 1.0000x reference)
//
#include <hip/hip_runtime.h>

#define N_PTS 16384
#define M_PTS 4096
#define D_INF 64
#define D_OUTF 128
#define KNN 16
#define DF 67   // 3 + 64

// ---------------- squared norms of p, numpy op order ----------------
__global__ __launch_bounds__(256) void sp_kernel(const float* __restrict__ p,
                                                 float* __restrict__ spn) {
  int j = blockIdx.x * 256 + threadIdx.x;
  float a = p[3 * j], b = p[3 * j + 1], c = p[3 * j + 2];
  spn[j] = __fadd_rn(__fadd_rn(__fmul_rn(a, a), __fmul_rn(b, b)), __fmul_rn(c, c));
}

// ---------------- FPS: single block, 1024 thr x 16 pts ----------------
// R1 (512x32, no bounds): VGPR=124, spilled -> 7.4ms. R2 (512x32, lb(512,2)):
// VGPR=84, spilled worse -> 9.2ms. Fix: shrink per-thread state to 64 floats
// so promotion fits the 128-VGPR cap of a 1024-thread block (4 waves/SIMD).
#define FPS_T 1024
#define FPS_PPT 16  // 1024*16 = 16384
#define FPS_W (FPS_T / 64)

__global__ __launch_bounds__(FPS_T) void fps_kernel(const float* __restrict__ p,
                                                    int* __restrict__ sidx,
                                                    float* __restrict__ np_out) {
  const int t = threadIdx.x;
  const int wave = t >> 6;
  const int lane = t & 63;
  float px[FPS_PPT], py[FPS_PPT], pz[FPS_PPT], dd[FPS_PPT];
#pragma unroll
  for (int k = 0; k < FPS_PPT; ++k) {
    int j = t + (k << 10);
    px[k] = p[3 * j]; py[k] = p[3 * j + 1]; pz[k] = p[3 * j + 2];
    dd[k] = INFINITY;
  }
  // double-buffered per-wave (value, index) winner pairs -> ONE barrier/iter
  __shared__ float s_v[2][FPS_W];
  __shared__ int s_i[2][FPS_W];
  float lx = p[0], ly = p[1], lz = p[2];  // first center = point 0
  if (t == 0) {
    sidx[0] = 0;
    np_out[0] = lx; np_out[1] = ly; np_out[2] = lz;
  }
  for (int i = 1; i < M_PTS; ++i) {
    const int b = i & 1;
    float bestv = -INFINITY;
    int besti = 0x7FFFFFFF;
#pragma unroll
    for (int k = 0; k < FPS_PPT; ++k) {
      // numpy order: ((dx*dx + dy*dy) + dz*dz), no fma contraction
      float dx = __fsub_rn(px[k], lx);
      float dy = __fsub_rn(py[k], ly);
      float dz = __fsub_rn(pz[k], lz);
      float d = __fadd_rn(__fadd_rn(__fmul_rn(dx, dx), __fmul_rn(dy, dy)),
                          __fmul_rn(dz, dz));
      float nd = fminf(dd[k], d);
      dd[k] = nd;
      // strict > keeps first occurrence (k ascending => global idx ascending)
      if (nd > bestv) besti = t + (k << 10);
      bestv = fmaxf(bestv, nd);
    }
    // wave-level lexicographic reduce: max value, then min index
#pragma unroll
    for (int off = 32; off >= 1; off >>= 1) {
      float ov = __shfl_xor(bestv, off);
      int oi = __shfl_xor(besti, off);
      if (ov > bestv || (ov == bestv && oi < besti)) { bestv = ov; besti = oi; }
    }
    if (lane == 0) { s_v[b][wave] = bestv; s_i[b][wave] = besti; }
    __syncthreads();  // the ONLY barrier per iteration
    float gv = s_v[b][0];
    int gi = s_i[b][0];
#pragma unroll
    for (int w = 1; w < FPS_W; ++w) {
      float vw = s_v[b][w];
      int iw = s_i[b][w];
      if (vw > gv || (vw == gv && iw < gi)) { gv = vw; gi = iw; }
    }
    // all lanes load winner coords from global (same addr -> one L1-hit request)
    lx = p[3 * gi]; ly = p[3 * gi + 1]; lz = p[3 * gi + 2];
    if (t == 0) {
      sidx[i] = gi;
      np_out[3 * i] = lx; np_out[3 * i + 1] = ly; np_out[3 * i + 2] = lz;
    }
  }
}

// ---------------- kNN + grouping + maxpool features: one wave per query ----
__global__ __launch_bounds__(256) void knn_feat_kernel(const float* __restrict__ p,
                                                       const float* __restrict__ x,
                                                       const float* __restrict__ spn,
                                                       const int* __restrict__ sidx,
                                                       float* __restrict__ feat) {
  __shared__ float cd[4][256];
  __shared__ int ci[4][256];
  __shared__ int cnt[4];
  __shared__ int s_nn[4][KNN];
  const int w = threadIdx.x >> 6;
  const int lane = threadIdx.x & 63;
  const int q = (blockIdx.x << 2) + w;
  const int qi = sidx[q];
  const float qx = p[3 * qi], qy = p[3 * qi + 1], qz = p[3 * qi + 2];
  const float sn = spn[qi];
  if (lane == 0) cnt[w] = 0;
  // Phase A: per-lane min distance over its 256 candidates
  float lmin = INFINITY;
  for (int it = 0; it < N_PTS / 64; ++it) {
    int j = lane + (it << 6);
    float dot = __fmaf_rn(qz, p[3 * j + 2],
                 __fmaf_rn(qy, p[3 * j + 1], __fmul_rn(qx, p[3 * j])));
    float d2 = __fsub_rn(__fadd_rn(sn, spn[j]), __fmul_rn(2.0f, dot));
    lmin = fminf(lmin, d2);
  }
  // tau = 16th smallest of 64 lane minima (valid upper bound on 16th NN dist)
  float mv = lmin;
  float tau = INFINITY;
#pragma unroll
  for (int r = 0; r < KNN; ++r) {
    float rmin = mv;
#pragma unroll
    for (int off = 32; off >= 1; off >>= 1) rmin = fminf(rmin, __shfl_xor(rmin, off));
    tau = rmin;
    unsigned long long msk = __ballot(mv == rmin);
    if (lane == (int)(__ffsll(msk) - 1)) mv = INFINITY;
  }
  __syncthreads();
  // Phase B: compact all candidates with d2 <= tau (expected ~18-40)
  for (int it = 0; it < N_PTS / 64; ++it) {
    int j = lane + (it << 6);
    float dot = __fmaf_rn(qz, p[3 * j + 2],
                 __fmaf_rn(qy, p[3 * j + 1], __fmul_rn(qx, p[3 * j])));
    float d2 = __fsub_rn(__fadd_rn(sn, spn[j]), __fmul_rn(2.0f, dot));
    if (d2 <= tau) {
      int pos = atomicAdd(&cnt[w], 1);
      if (pos < 256) { cd[w][pos] = d2; ci[w][pos] = j; }
    }
  }
  __syncthreads();
  // Phase C: extract 16 smallest by (value, index) — stable top_k semantics
  int C = min(cnt[w], 256);
  float vv[4]; int ii[4];
#pragma unroll
  for (int s = 0; s < 4; ++s) {
    int pos = lane + (s << 6);
    bool ok = pos < C;
    vv[s] = ok ? cd[w][pos] : INFINITY;
    ii[s] = ok ? ci[w][pos] : 0x7FFFFFFF;
  }
#pragma unroll
  for (int r = 0; r < KNN; ++r) {
    float bv = vv[0]; int bi = ii[0]; int bs = 0;
#pragma unroll
    for (int s = 1; s < 4; ++s) {
      bool tk = (vv[s] < bv) || (vv[s] == bv && ii[s] < bi);
      bv = tk ? vv[s] : bv; bi = tk ? ii[s] : bi; bs = tk ? s : bs;
    }
    float rv = bv; int ri = bi;
#pragma unroll
    for (int off = 32; off >= 1; off >>= 1) {
      float ov = __shfl_xor(rv, off); int oi = __shfl_xor(ri, off);
      bool tk = (ov < rv) || (ov == rv && oi < ri);
      rv = tk ? ov : rv; ri = tk ? oi : ri;
    }
    if (bi == ri) {  // my local-best slot won: retire it
#pragma unroll
      for (int s = 0; s < 4; ++s) if (s == bs) vv[s] = INFINITY;
    }
    if (lane == 0) s_nn[w][r] = ri;
  }
  __syncthreads();
  // Phase D: relative coords, norm scaling, maxpool
  float ax = -INFINITY, ay = -INFINITY, az = -INFINITY, nr = -INFINITY;
  if (lane < KNN) {
    int jn = s_nn[w][lane];
    ax = __fsub_rn(p[3 * jn], qx);
    ay = __fsub_rn(p[3 * jn + 1], qy);
    az = __fsub_rn(p[3 * jn + 2], qz);
    nr = sqrtf(__fadd_rn(__fadd_rn(__fmul_rn(ax, ax), __fmul_rn(ay, ay)),
                         __fmul_rn(az, az)));
  }
  float mnr = nr, mx = ax, my = ay, mz = az;
#pragma unroll
  for (int off = 32; off >= 1; off >>= 1) {
    mnr = fmaxf(mnr, __shfl_xor(mnr, off));
    mx = fmaxf(mx, __shfl_xor(mx, off));
    my = fmaxf(my, __shfl_xor(my, off));
    mz = fmaxf(mz, __shfl_xor(mz, off));
  }
  if (lane == 0) {
    // max over k commutes exactly with the (monotone) division
    float sden = __fadd_rn(mnr, 1e-8f);
    feat[q * DF + 0] = mx / sden;
    feat[q * DF + 1] = my / sden;
    feat[q * DF + 2] = mz / sden;
  }
  float fm = -INFINITY;
#pragma unroll
  for (int k = 0; k < KNN; ++k) {
    int jn = s_nn[w][k];
    fm = fmaxf(fm, x[(jn << 6) + lane]);
  }
  feat[q * DF + 3 + lane] = fm;
}

// ---------------- MLP: h = feat @ W + b ----------------
__global__ __launch_bounds__(128) void mlp_kernel(const float* __restrict__ feat,
                                                  const float* __restrict__ W,
                                                  const float* __restrict__ b,
                                                  float* __restrict__ h) {
  int mrow = blockIdx.x;
  int o = threadIdx.x;
  const float* fr = feat + mrow * DF;
  float acc = b[o];
#pragma unroll
  for (int k = 0; k < DF; ++k) acc = __fmaf_rn(fr[k], W[k * D_OUTF + o], acc);
  h[mrow * D_OUTF + o] = acc;
}

// ---------------- BN column stats (training mode) ----------------
__global__ __launch_bounds__(256) void stats_kernel(const float* __restrict__ h,
                                                    const float* __restrict__ gamma,
                                                    const float* __restrict__ beta,
                                                    float* __restrict__ scsh) {
  int o = blockIdx.x;
  int t = threadIdx.x;
  float s = 0.f, s2 = 0.f;
  for (int mrow = t; mrow < M_PTS; mrow += 256) {
    float v = h[mrow * D_OUTF + o];
    s += v;
    s2 = __fmaf_rn(v, v, s2);
  }
#pragma unroll
  for (int off = 32; off >= 1; off >>= 1) {
    s += __shfl_xor(s, off);
    s2 += __shfl_xor(s2, off);
  }
  __shared__ float as1[4], as2[4];
  if ((t & 63) == 0) { as1[t >> 6] = s; as2[t >> 6] = s2; }
  __syncthreads();
  if (t == 0) {
    float ts = ((as1[0] + as1[1]) + as1[2]) + as1[3];
    float ts2 = ((as2[0] + as2[1]) + as2[2]) + as2[3];
    float mean = ts / (float)M_PTS;
    float var = ts2 / (float)M_PTS - mean * mean;
    var = fmaxf(var, 0.f);
    float sc = gamma[o] / sqrtf(var + 1e-5f);
    scsh[o] = sc;
    scsh[D_OUTF + o] = beta[o] - mean * sc;
  }
}

// ---------------- BN apply + ReLU + n_o ----------------
__global__ __launch_bounds__(256) void bn_kernel(const float* __restrict__ h,
                                                 const float* __restrict__ scsh,
                                                 float* __restrict__ out) {
  int idx = blockIdx.x * 256 + threadIdx.x;
  int o = idx & (D_OUTF - 1);
  float v = __fmaf_rn(h[idx], scsh[o], scsh[D_OUTF + o]);
  out[M_PTS * 3 + idx] = fmaxf(v, 0.f);
  if (idx == 0) out[M_PTS * 3 + M_PTS * D_OUTF] = 4096.0f;  // n_o
}

extern "C" void kernel_launch(void* const* d_in, const int* in_sizes, int n_in,
                              void* d_out, int out_size, void* d_ws, size_t ws_size,
                              hipStream_t stream) {
  const float* p     = (const float*)d_in[0];
  const float* x     = (const float*)d_in[1];
  // d_in[2] = o (offsets) — unused, single cloud
  const float* W     = (const float*)d_in[3];
  const float* b     = (const float*)d_in[4];
  const float* gamma = (const float*)d_in[5];
  const float* beta  = (const float*)d_in[6];
  float* out = (float*)d_out;

  float* wsf  = (float*)d_ws;
  int*   sidx = (int*)d_ws;                    // [4096]
  float* spn  = wsf + 4096;                    // [16384]
  float* feat = spn + N_PTS;                   // [4096 * 67]
  float* h    = feat + M_PTS * DF;             // [4096 * 128]
  float* scsh = h + M_PTS * D_OUTF;            // [256]

  sp_kernel<<<N_PTS / 256, 256, 0, stream>>>(p, spn);
  fps_kernel<<<1, FPS_T, 0, stream>>>(p, sidx, out);
  knn_feat_kernel<<<M_PTS / 4, 256, 0, stream>>>(p, x, spn, sidx, feat);
  mlp_kernel<<<M_PTS, D_OUTF, 0, stream>>>(feat, W, b, h);
  stats_kernel<<<D_OUTF, 256, 0, stream>>>(h, gamma, beta, scsh);
  bn_kernel<<<(M_PTS * D_OUTF) / 256, 256, 0, stream>>>(h, scsh, out);
}

// Round 4
// 8479.530 us; speedup vs baseline: 1.4219x; 1.4219x over previous
//
#include <hip/hip_runtime.h>

#define N_PTS 16384
#define M_PTS 4096
#define D_INF 64
#define D_OUTF 128
#define KNN 16
#define DF 67   // 3 + 64

// ---------------- squared norms of p, numpy op order ----------------
__global__ __launch_bounds__(256) void sp_kernel(const float* __restrict__ p,
                                                 float* __restrict__ spn) {
  int j = blockIdx.x * 256 + threadIdx.x;
  float a = p[3 * j], b = p[3 * j + 1], c = p[3 * j + 2];
  spn[j] = __fadd_rn(__fadd_rn(__fmul_rn(a, a), __fmul_rn(b, b)), __fmul_rn(c, c));
}

// ---------------- FPS: single block, 1024 thr x 16 NAMED-SCALAR pts -------
// R1-R3: float arrays were never register-promoted (VGPR_Count 124/84/48,
// scratch-L2 bound ~3us/iter). Fix: 64 named SSA floats (cannot be alloca'd)
// + __launch_bounds__(1024,4) = 1 block/CU -> 128-VGPR cap, ~95 live regs fit.
#define FPS_T 1024
#define FPS_W (FPS_T / 64)

#define REP16(F) F(0) F(1) F(2) F(3) F(4) F(5) F(6) F(7) \
                 F(8) F(9) F(10) F(11) F(12) F(13) F(14) F(15)

__global__ __launch_bounds__(FPS_T, 4) void fps_kernel(const float* __restrict__ p,
                                                       int* __restrict__ sidx,
                                                       float* __restrict__ np_out) {
  const int t = threadIdx.x;
  const int lane = t & 63;
  const int wave = t >> 6;

#define FPS_DECL(k) float px##k, py##k, pz##k, dd##k;
  REP16(FPS_DECL)
#define FPS_LOAD(k) { int j = t + (k << 10); \
    px##k = p[3 * j]; py##k = p[3 * j + 1]; pz##k = p[3 * j + 2]; \
    dd##k = INFINITY; }
  REP16(FPS_LOAD)

  // double-buffered per-wave packed (value,index) keys -> ONE barrier/iter
  __shared__ unsigned long long s_key[2][FPS_W];

  float lx = p[0], ly = p[1], lz = p[2];  // first center = point 0
  if (t == 0) {
    sidx[0] = 0;
    np_out[0] = lx; np_out[1] = ly; np_out[2] = lz;
  }
  for (int i = 1; i < M_PTS; ++i) {
    const int bsel = i & 1;
    float bestv = -1.0f;
    int besti = 0;
    // numpy order: ((dx*dx + dy*dy) + dz*dz), no fma contraction.
    // strict > keeps first occurrence (k ascending => global idx ascending)
#define FPS_STEP(k) { \
    float dx = __fsub_rn(px##k, lx); \
    float dy = __fsub_rn(py##k, ly); \
    float dz = __fsub_rn(pz##k, lz); \
    float d = __fadd_rn(__fadd_rn(__fmul_rn(dx, dx), __fmul_rn(dy, dy)), \
                        __fmul_rn(dz, dz)); \
    float nd = fminf(dd##k, d); \
    dd##k = nd; \
    if (nd > bestv) { bestv = nd; besti = t + (k << 10); } }
    REP16(FPS_STEP)
    // pack: dists >= 0 so float bits are unsigned-monotone; ~idx gives
    // min-index on value ties under unsigned max. One u64 max = argmax.
    unsigned long long key =
        ((unsigned long long)__float_as_uint(bestv) << 32) |
        (unsigned int)(~besti);
#pragma unroll
    for (int off = 32; off >= 1; off >>= 1) {
      unsigned long long ok = __shfl_xor(key, off);
      key = (ok > key) ? ok : key;
    }
    if (lane == 0) s_key[bsel][wave] = key;
    __syncthreads();  // the ONLY barrier per iteration
    unsigned long long kk = s_key[bsel][lane & (FPS_W - 1)];
#pragma unroll
    for (int off = 32; off >= 1; off >>= 1) {
      unsigned long long ok = __shfl_xor(kk, off);
      kk = (ok > kk) ? ok : kk;
    }
    int gi = (int)(~(unsigned int)kk);
    // all lanes load winner coords (same addr -> one L1-hit broadcast)
    lx = p[3 * gi]; ly = p[3 * gi + 1]; lz = p[3 * gi + 2];
    if (t == 0) {
      sidx[i] = gi;
      np_out[3 * i] = lx; np_out[3 * i + 1] = ly; np_out[3 * i + 2] = lz;
    }
  }
}

// ---------------- kNN + grouping + maxpool features: one wave per query ----
__global__ __launch_bounds__(256) void knn_feat_kernel(const float* __restrict__ p,
                                                       const float* __restrict__ x,
                                                       const float* __restrict__ spn,
                                                       const int* __restrict__ sidx,
                                                       float* __restrict__ feat) {
  __shared__ float cd[4][256];
  __shared__ int ci[4][256];
  __shared__ int cnt[4];
  __shared__ int s_nn[4][KNN];
  const int w = threadIdx.x >> 6;
  const int lane = threadIdx.x & 63;
  const int q = (blockIdx.x << 2) + w;
  const int qi = sidx[q];
  const float qx = p[3 * qi], qy = p[3 * qi + 1], qz = p[3 * qi + 2];
  const float sn = spn[qi];
  if (lane == 0) cnt[w] = 0;
  // Phase A: per-lane min distance over its 256 candidates
  float lmin = INFINITY;
  for (int it = 0; it < N_PTS / 64; ++it) {
    int j = lane + (it << 6);
    float dot = __fmaf_rn(qz, p[3 * j + 2],
                 __fmaf_rn(qy, p[3 * j + 1], __fmul_rn(qx, p[3 * j])));
    float d2 = __fsub_rn(__fadd_rn(sn, spn[j]), __fmul_rn(2.0f, dot));
    lmin = fminf(lmin, d2);
  }
  // tau = 16th smallest of 64 lane minima (valid upper bound on 16th NN dist)
  float mv = lmin;
  float tau = INFINITY;
#pragma unroll
  for (int r = 0; r < KNN; ++r) {
    float rmin = mv;
#pragma unroll
    for (int off = 32; off >= 1; off >>= 1) rmin = fminf(rmin, __shfl_xor(rmin, off));
    tau = rmin;
    unsigned long long msk = __ballot(mv == rmin);
    if (lane == (int)(__ffsll(msk) - 1)) mv = INFINITY;
  }
  __syncthreads();
  // Phase B: compact all candidates with d2 <= tau (expected ~18-40)
  for (int it = 0; it < N_PTS / 64; ++it) {
    int j = lane + (it << 6);
    float dot = __fmaf_rn(qz, p[3 * j + 2],
                 __fmaf_rn(qy, p[3 * j + 1], __fmul_rn(qx, p[3 * j])));
    float d2 = __fsub_rn(__fadd_rn(sn, spn[j]), __fmul_rn(2.0f, dot));
    if (d2 <= tau) {
      int pos = atomicAdd(&cnt[w], 1);
      if (pos < 256) { cd[w][pos] = d2; ci[w][pos] = j; }
    }
  }
  __syncthreads();
  // Phase C: extract 16 smallest by (value, index) — stable top_k semantics
  int C = min(cnt[w], 256);
  float vv[4]; int ii[4];
#pragma unroll
  for (int s = 0; s < 4; ++s) {
    int pos = lane + (s << 6);
    bool ok = pos < C;
    vv[s] = ok ? cd[w][pos] : INFINITY;
    ii[s] = ok ? ci[w][pos] : 0x7FFFFFFF;
  }
#pragma unroll
  for (int r = 0; r < KNN; ++r) {
    float bv = vv[0]; int bi = ii[0]; int bs = 0;
#pragma unroll
    for (int s = 1; s < 4; ++s) {
      bool tk = (vv[s] < bv) || (vv[s] == bv && ii[s] < bi);
      bv = tk ? vv[s] : bv; bi = tk ? ii[s] : bi; bs = tk ? s : bs;
    }
    float rv = bv; int ri = bi;
#pragma unroll
    for (int off = 32; off >= 1; off >>= 1) {
      float ov = __shfl_xor(rv, off); int oi = __shfl_xor(ri, off);
      bool tk = (ov < rv) || (ov == rv && oi < ri);
      rv = tk ? ov : rv; ri = tk ? oi : ri;
    }
    if (bi == ri) {  // my local-best slot won: retire it
#pragma unroll
      for (int s = 0; s < 4; ++s) if (s == bs) vv[s] = INFINITY;
    }
    if (lane == 0) s_nn[w][r] = ri;
  }
  __syncthreads();
  // Phase D: relative coords, norm scaling, maxpool
  float ax = -INFINITY, ay = -INFINITY, az = -INFINITY, nr = -INFINITY;
  if (lane < KNN) {
    int jn = s_nn[w][lane];
    ax = __fsub_rn(p[3 * jn], qx);
    ay = __fsub_rn(p[3 * jn + 1], qy);
    az = __fsub_rn(p[3 * jn + 2], qz);
    nr = sqrtf(__fadd_rn(__fadd_rn(__fmul_rn(ax, ax), __fmul_rn(ay, ay)),
                         __fmul_rn(az, az)));
  }
  float mnr = nr, mx = ax, my = ay, mz = az;
#pragma unroll
  for (int off = 32; off >= 1; off >>= 1) {
    mnr = fmaxf(mnr, __shfl_xor(mnr, off));
    mx = fmaxf(mx, __shfl_xor(mx, off));
    my = fmaxf(my, __shfl_xor(my, off));
    mz = fmaxf(mz, __shfl_xor(mz, off));
  }
  if (lane == 0) {
    // max over k commutes exactly with the (monotone) division
    float sden = __fadd_rn(mnr, 1e-8f);
    feat[q * DF + 0] = mx / sden;
    feat[q * DF + 1] = my / sden;
    feat[q * DF + 2] = mz / sden;
  }
  float fm = -INFINITY;
#pragma unroll
  for (int k = 0; k < KNN; ++k) {
    int jn = s_nn[w][k];
    fm = fmaxf(fm, x[(jn << 6) + lane]);
  }
  feat[q * DF + 3 + lane] = fm;
}

// ---------------- MLP: h = feat @ W + b ----------------
__global__ __launch_bounds__(128) void mlp_kernel(const float* __restrict__ feat,
                                                  const float* __restrict__ W,
                                                  const float* __restrict__ b,
                                                  float* __restrict__ h) {
  int mrow = blockIdx.x;
  int o = threadIdx.x;
  const float* fr = feat + mrow * DF;
  float acc = b[o];
#pragma unroll
  for (int k = 0; k < DF; ++k) acc = __fmaf_rn(fr[k], W[k * D_OUTF + o], acc);
  h[mrow * D_OUTF + o] = acc;
}

// ---------------- BN column stats (training mode) ----------------
__global__ __launch_bounds__(256) void stats_kernel(const float* __restrict__ h,
                                                    const float* __restrict__ gamma,
                                                    const float* __restrict__ beta,
                                                    float* __restrict__ scsh) {
  int o = blockIdx.x;
  int t = threadIdx.x;
  float s = 0.f, s2 = 0.f;
  for (int mrow = t; mrow < M_PTS; mrow += 256) {
    float v = h[mrow * D_OUTF + o];
    s += v;
    s2 = __fmaf_rn(v, v, s2);
  }
#pragma unroll
  for (int off = 32; off >= 1; off >>= 1) {
    s += __shfl_xor(s, off);
    s2 += __shfl_xor(s2, off);
  }
  __shared__ float as1[4], as2[4];
  if ((t & 63) == 0) { as1[t >> 6] = s; as2[t >> 6] = s2; }
  __syncthreads();
  if (t == 0) {
    float ts = ((as1[0] + as1[1]) + as1[2]) + as1[3];
    float ts2 = ((as2[0] + as2[1]) + as2[2]) + as2[3];
    float mean = ts / (float)M_PTS;
    float var = ts2 / (float)M_PTS - mean * mean;
    var = fmaxf(var, 0.f);
    float sc = gamma[o] / sqrtf(var + 1e-5f);
    scsh[o] = sc;
    scsh[D_OUTF + o] = beta[o] - mean * sc;
  }
}

// ---------------- BN apply + ReLU + n_o ----------------
__global__ __launch_bounds__(256) void bn_kernel(const float* __restrict__ h,
                                                 const float* __restrict__ scsh,
                                                 float* __restrict__ out) {
  int idx = blockIdx.x * 256 + threadIdx.x;
  int o = idx & (D_OUTF - 1);
  float v = __fmaf_rn(h[idx], scsh[o], scsh[D_OUTF + o]);
  out[M_PTS * 3 + idx] = fmaxf(v, 0.f);
  if (idx == 0) out[M_PTS * 3 + M_PTS * D_OUTF] = 4096.0f;  // n_o
}

extern "C" void kernel_launch(void* const* d_in, const int* in_sizes, int n_in,
                              void* d_out, int out_size, void* d_ws, size_t ws_size,
                              hipStream_t stream) {
  const float* p     = (const float*)d_in[0];
  const float* x     = (const float*)d_in[1];
  // d_in[2] = o (offsets) — unused, single cloud
  const float* W     = (const float*)d_in[3];
  const float* b     = (const float*)d_in[4];
  const float* gamma = (const float*)d_in[5];
  const float* beta  = (const float*)d_in[6];
  float* out = (float*)d_out;

  float* wsf  = (float*)d_ws;
  int*   sidx = (int*)d_ws;                    // [4096]
  float* spn  = wsf + 4096;                    // [16384]
  float* feat = spn + N_PTS;                   // [4096 * 67]
  float* h    = feat + M_PTS * DF;             // [4096 * 128]
  float* scsh = h + M_PTS * D_OUTF;            // [256]

  sp_kernel<<<N_PTS / 256, 256, 0, stream>>>(p, spn);
  fps_kernel<<<1, FPS_T, 0, stream>>>(p, sidx, out);
  knn_feat_kernel<<<M_PTS / 4, 256, 0, stream>>>(p, x, spn, sidx, feat);
  mlp_kernel<<<M_PTS, D_OUTF, 0, stream>>>(feat, W, b, h);
  stats_kernel<<<D_OUTF, 256, 0, stream>>>(h, gamma, beta, scsh);
  bn_kernel<<<(M_PTS * D_OUTF) / 256, 256, 0, stream>>>(h, scsh, out);
}